// Round 5
// baseline (106.378 us; speedup 1.0000x reference)
//
#include <hip/hip_runtime.h>
#include <stdint.h>

#define N_CLS 8192
#define FEAT  512
#define BATCH 1024
#define TILE  256
#define NSLOT 16                            // FEAT / 32
#define NTILE (N_CLS / TILE)                // 32
#define NBLK  (NTILE * (NTILE + 1) / 2)     // 528
#define SLOT_SH 16384                       // shorts per ring slot (32 KiB)

typedef __attribute__((ext_vector_type(8))) short short8;
typedef __attribute__((ext_vector_type(4))) float f32x4;

__device__ inline unsigned short f2bf(float x) {
    union { float f; unsigned int u; } v; v.f = x;
    unsigned int u = v.u;
    u += 0x7fffu + ((u >> 16) & 1u);        // RNE to bf16
    return (unsigned short)(u >> 16);
}

// ---------------- Kernel 1: sequential EMA per label -> bf16 protos --------
__global__ __launch_bounds__(256) void ema_kernel(
    const float* __restrict__ features, const int* __restrict__ labels,
    const float* __restrict__ protos,
    unsigned short* __restrict__ Phi, float* __restrict__ rowsum) {
    const int row  = blockIdx.x * 4 + (threadIdx.x >> 6);
    const int lane = threadIdx.x & 63;
    if (lane == 0) rowsum[row] = 0.f;

    float p[8];
    #pragma unroll
    for (int j = 0; j < 8; ++j) p[j] = protos[(size_t)row * FEAT + j * 64 + lane];

    for (int c = 0; c < BATCH / 64; ++c) {
        int lab = labels[c * 64 + lane];
        unsigned long long m = __ballot(lab == row);
        while (m) {
            int b = __builtin_ctzll(m);     // earliest remaining sample
            m &= m - 1;
            int s = c * 64 + b;
            float ss = 0.f;
            #pragma unroll
            for (int j = 0; j < 8; ++j) {
                float f = features[(size_t)s * FEAT + j * 64 + lane];
                p[j] = p[j] * 0.95f + f * 0.05f;
                ss += p[j] * p[j];
            }
            #pragma unroll
            for (int off = 32; off; off >>= 1) ss += __shfl_xor(ss, off);
            float inv = 1.0f / fmaxf(sqrtf(ss), 1e-12f);
            #pragma unroll
            for (int j = 0; j < 8; ++j) p[j] *= inv;
        }
    }
    #pragma unroll
    for (int j = 0; j < 8; ++j)
        Phi[(size_t)row * FEAT + j * 64 + lane] = f2bf(p[j]);
}

// ---------------- Kernel 2: 256^2 Gram tiles, 8-phase ring pipeline --------
// Ring of 4 K-32 slots; staging 3 slots ahead; vmcnt(8) counted waits (never
// 0 in main loop); 2 raw barriers per phase; setprio around MFMA clusters.
__global__ __launch_bounds__(512, 2) void gemm_disp_kernel(
    const unsigned short* __restrict__ Phi, float* __restrict__ rowsum) {
    __shared__ short smem[4 * SLOT_SH];     // 128 KiB

    // XCD-aware swizzle (528 = 8*66, divisible -> bijective)
    int bid = blockIdx.x;
    int swz = (bid & 7) * (NBLK / 8) + (bid >> 3);
    int t = swz, I = 0;
    while (t >= NTILE - I) { t -= NTILE - I; ++I; }
    const int J = I + t;                    // J >= I

    const int w    = threadIdx.x >> 6;      // wave 0..7
    const int lane = threadIdx.x & 63;
    const int wr = w >> 2, wc = w & 3;      // 2x4 waves, 128x64 output each
    const int h = lane >> 4;                // k-group 0..3
    const int r = lane & 15;                // fragment row/col
    const int segA = ((h ^ ((r >> 1) & 3)) * 8); // swizzled read segment (shorts)

    const int Ibase = I * TILE, Jbase = J * TILE;

    f32x4 acc[8][4];
    #pragma unroll
    for (int m = 0; m < 8; ++m)
        #pragma unroll
        for (int n = 0; n < 4; ++n) acc[m][n] = (f32x4){0.f, 0.f, 0.f, 0.f};

    // staging: 4 groups per slot (A lo/hi 128 rows, B lo/hi); wave w covers
    // rows [w*16, w*16+16) of each group; linear LDS dest, pre-swizzled src.
    const int srow = lane >> 2;             // 0..15
    const int sseg = (lane & 3) ^ ((srow >> 1) & 3);
    const unsigned short* gA =
        Phi + (size_t)(Ibase + w * 16 + srow) * FEAT + sseg * 8;
    const unsigned short* gB =
        Phi + (size_t)(Jbase + w * 16 + srow) * FEAT + sseg * 8;

#define STAGE_G(slot, g)                                                      \
    {                                                                         \
        const unsigned short* gsrc = ((g) < 2 ? gA : gB)                      \
            + (size_t)(((g) & 1) * 128) * FEAT + (slot) * 32;                 \
        short* ldst = smem + ((slot) & 3) * SLOT_SH + ((g) < 2 ? 0 : 8192)    \
                    + (((g) & 1) * 128 + w * 16) * 32;                        \
        __builtin_amdgcn_global_load_lds(                                     \
            (const __attribute__((address_space(1))) void*)gsrc,              \
            (__attribute__((address_space(3))) void*)ldst, 16, 0, 0);         \
    }

#define MF4(ai, mi)                                                           \
    acc[mi][0] = __builtin_amdgcn_mfma_f32_16x16x32_bf16(ai, b0, acc[mi][0], 0, 0, 0); \
    acc[mi][1] = __builtin_amdgcn_mfma_f32_16x16x32_bf16(ai, b1, acc[mi][1], 0, 0, 0); \
    acc[mi][2] = __builtin_amdgcn_mfma_f32_16x16x32_bf16(ai, b2, acc[mi][2], 0, 0, 0); \
    acc[mi][3] = __builtin_amdgcn_mfma_f32_16x16x32_bf16(ai, b3, acc[mi][3], 0, 0, 0);

#define SLOT_BODY(s, DO_STAGE, VMSTR)                                         \
    {                                                                         \
        const short* As = smem + ((s) & 3) * SLOT_SH;                         \
        const short* Bs = As + 8192;                                          \
        short8 a0, a1, a2, a3, b0, b1, b2, b3;                                \
        /* -- even phase: A rows wr*128+[0,64), all B -- */                   \
        b0 = *(const short8*)(Bs + (wc * 64 +  0 + r) * 32 + segA);           \
        b1 = *(const short8*)(Bs + (wc * 64 + 16 + r) * 32 + segA);           \
        b2 = *(const short8*)(Bs + (wc * 64 + 32 + r) * 32 + segA);           \
        b3 = *(const short8*)(Bs + (wc * 64 + 48 + r) * 32 + segA);           \
        a0 = *(const short8*)(As + (wr * 128 +  0 + r) * 32 + segA);          \
        a1 = *(const short8*)(As + (wr * 128 + 16 + r) * 32 + segA);          \
        a2 = *(const short8*)(As + (wr * 128 + 32 + r) * 32 + segA);          \
        a3 = *(const short8*)(As + (wr * 128 + 48 + r) * 32 + segA);          \
        if (DO_STAGE) { STAGE_G((s) + 3, 0); STAGE_G((s) + 3, 1); }           \
        __builtin_amdgcn_s_barrier();                                         \
        asm volatile("s_waitcnt lgkmcnt(0)" ::: "memory");                    \
        __builtin_amdgcn_sched_barrier(0);                                    \
        __builtin_amdgcn_s_setprio(1);                                        \
        MF4(a0, 0) MF4(a1, 1) MF4(a2, 2) MF4(a3, 3)                           \
        __builtin_amdgcn_s_setprio(0);                                        \
        __builtin_amdgcn_s_barrier();                                         \
        /* -- odd phase: A rows wr*128+[64,128), B reused in regs -- */       \
        a0 = *(const short8*)(As + (wr * 128 +  64 + r) * 32 + segA);         \
        a1 = *(const short8*)(As + (wr * 128 +  80 + r) * 32 + segA);         \
        a2 = *(const short8*)(As + (wr * 128 +  96 + r) * 32 + segA);         \
        a3 = *(const short8*)(As + (wr * 128 + 112 + r) * 32 + segA);         \
        if (DO_STAGE) { STAGE_G((s) + 3, 2); STAGE_G((s) + 3, 3); }           \
        asm volatile(VMSTR ::: "memory");                                     \
        __builtin_amdgcn_s_barrier();                                         \
        asm volatile("s_waitcnt lgkmcnt(0)" ::: "memory");                    \
        __builtin_amdgcn_sched_barrier(0);                                    \
        __builtin_amdgcn_s_setprio(1);                                        \
        MF4(a0, 4) MF4(a1, 5) MF4(a2, 6) MF4(a3, 7)                           \
        __builtin_amdgcn_s_setprio(0);                                        \
        __builtin_amdgcn_s_barrier();                                         \
    }

    // prologue: stage slots 0,1,2 (12 loads/wave); wait slot 0 (8 remain)
    #pragma unroll
    for (int s0 = 0; s0 < 3; ++s0) {
        STAGE_G(s0, 0); STAGE_G(s0, 1); STAGE_G(s0, 2); STAGE_G(s0, 3);
    }
    asm volatile("s_waitcnt vmcnt(8)" ::: "memory");
    __builtin_amdgcn_s_barrier();

    for (int s = 0; s < NSLOT - 3; ++s)     // s = 0..12, steady vmcnt(8)
        SLOT_BODY(s, 1, "s_waitcnt vmcnt(8)");
    SLOT_BODY(13, 0, "s_waitcnt vmcnt(4)"); // slot 15 still in flight
    SLOT_BODY(14, 0, "s_waitcnt vmcnt(0)"); // drain: last slot landed
    SLOT_BODY(15, 0, "");                   // nothing outstanding

    // epilogue: e = exp(10*S), zero diagonal, reduce, atomics
    // D layout: row = 4*h + q, col = r (HW-verified)
    #pragma unroll
    for (int m = 0; m < 8; ++m)
        #pragma unroll
        for (int n = 0; n < 4; ++n)
            #pragma unroll
            for (int q = 0; q < 4; ++q) {
                float v = __expf(acc[m][n][q] * 10.0f);
                if (I == J &&
                    (wr * 128 + m * 16 + h * 4 + q) == (wc * 64 + n * 16 + r))
                    v = 0.f;
                acc[m][n][q] = v;
            }

    // row sums -> rowsum[Ibase + wr*128 + m*16 + 4h+q]
    #pragma unroll
    for (int m = 0; m < 8; ++m) {
        float rs[4];
        #pragma unroll
        for (int q = 0; q < 4; ++q)
            rs[q] = acc[m][0][q] + acc[m][1][q] + acc[m][2][q] + acc[m][3][q];
        #pragma unroll
        for (int q = 0; q < 4; ++q)
            #pragma unroll
            for (int off = 1; off < 16; off <<= 1) rs[q] += __shfl_xor(rs[q], off);
        if (r == 0) {
            #pragma unroll
            for (int q = 0; q < 4; ++q)
                atomicAdd(&rowsum[Ibase + wr * 128 + m * 16 + h * 4 + q], rs[q]);
        }
    }

    // col sums (symmetry) -> rowsum[Jbase + wc*64 + n*16 + r]
    if (I != J) {
        #pragma unroll
        for (int n = 0; n < 4; ++n) {
            float cs = 0.f;
            #pragma unroll
            for (int m = 0; m < 8; ++m)
                #pragma unroll
                for (int q = 0; q < 4; ++q) cs += acc[m][n][q];
            cs += __shfl_xor(cs, 16);
            cs += __shfl_xor(cs, 32);
            if (lane < 16)
                atomicAdd(&rowsum[Jbase + wc * 64 + n * 16 + r], cs);
        }
    }
}

// ---------------- Kernel 3: loss = mean(log(rowsum / (n-1))) ---------------
__global__ __launch_bounds__(512) void loss_kernel(
    const float* __restrict__ rowsum, float* __restrict__ out) {
    __shared__ float red[8];
    float s = 0.f;
    for (int i = threadIdx.x; i < N_CLS; i += 512)
        s += logf(rowsum[i] * (1.0f / (float)(N_CLS - 1)));
    #pragma unroll
    for (int off = 32; off; off >>= 1) s += __shfl_xor(s, off);
    if ((threadIdx.x & 63) == 0) red[threadIdx.x >> 6] = s;
    __syncthreads();
    if (threadIdx.x == 0) {
        float tot = 0.f;
        #pragma unroll
        for (int i = 0; i < 8; ++i) tot += red[i];
        out[0] = tot * (1.0f / (float)N_CLS);
    }
}

extern "C" void kernel_launch(void* const* d_in, const int* in_sizes, int n_in,
                              void* d_out, int out_size, void* d_ws, size_t ws_size,
                              hipStream_t stream) {
    (void)in_sizes; (void)n_in; (void)out_size; (void)ws_size;
    const float* features = (const float*)d_in[0];
    const int*   labels   = (const int*)d_in[1];
    const float* protos   = (const float*)d_in[2];
    float* out = (float*)d_out;

    unsigned short* Phi = (unsigned short*)d_ws;                    // 8 MiB
    float* rowsum = (float*)(Phi + (size_t)N_CLS * FEAT);           // 32 KiB

    ema_kernel<<<N_CLS / 4, 256, 0, stream>>>(features, labels, protos, Phi, rowsum);
    gemm_disp_kernel<<<NBLK, 512, 0, stream>>>(Phi, rowsum);
    loss_kernel<<<1, 512, 0, stream>>>(rowsum, out);
}

// Round 6
// 81.002 us; speedup vs baseline: 1.3133x; 1.3133x over previous
//
#include <hip/hip_runtime.h>
#include <stdint.h>

#define N_CLS 8192
#define FEAT  512
#define BATCH 1024
#define NTI   32                            // 256-row tiles
#define NTJ   64                            // 128-col tiles
#define NBLK  1056                          // #{(i,j): j in [2i, 64)}
#define NSLOT 16                            // FEAT/32
#define BUFSH 12288                         // shorts per buf: A 256*32 + B 128*32

typedef __attribute__((ext_vector_type(8))) short short8;
typedef __attribute__((ext_vector_type(4))) float f32x4;

__device__ inline unsigned short f2bf(float x) {
    union { float f; unsigned int u; } v; v.f = x;
    unsigned int u = v.u;
    u += 0x7fffu + ((u >> 16) & 1u);        // RNE to bf16
    return (unsigned short)(u >> 16);
}

// ---------------- Kernel 1: sequential EMA per label -> bf16 protos --------
__global__ __launch_bounds__(256) void ema_kernel(
    const float* __restrict__ features, const int* __restrict__ labels,
    const float* __restrict__ protos,
    unsigned short* __restrict__ Phi, float* __restrict__ rowsum) {
    const int row  = blockIdx.x * 4 + (threadIdx.x >> 6);
    const int lane = threadIdx.x & 63;
    if (lane == 0) rowsum[row] = 0.f;

    float p[8];
    #pragma unroll
    for (int j = 0; j < 8; ++j) p[j] = protos[(size_t)row * FEAT + j * 64 + lane];

    for (int c = 0; c < BATCH / 64; ++c) {
        int lab = labels[c * 64 + lane];
        unsigned long long m = __ballot(lab == row);
        while (m) {
            int b = __builtin_ctzll(m);     // earliest remaining sample
            m &= m - 1;
            int s = c * 64 + b;
            float ss = 0.f;
            #pragma unroll
            for (int j = 0; j < 8; ++j) {
                float f = features[(size_t)s * FEAT + j * 64 + lane];
                p[j] = p[j] * 0.95f + f * 0.05f;
                ss += p[j] * p[j];
            }
            #pragma unroll
            for (int off = 32; off; off >>= 1) ss += __shfl_xor(ss, off);
            float inv = 1.0f / fmaxf(sqrtf(ss), 1e-12f);
            #pragma unroll
            for (int j = 0; j < 8; ++j) p[j] *= inv;
        }
    }
    #pragma unroll
    for (int j = 0; j < 8; ++j)
        Phi[(size_t)row * FEAT + j * 64 + lane] = f2bf(p[j]);
}

// ---------------- Kernel 2: 256x128 rect Gram tiles, 2 blocks/CU -----------
// 8 waves of 64x64; acc[4][4]=64 AGPR -> ~115 unified regs -> 16 waves/CU.
// BK=32 double-buffered (48 KiB). Stage next slot between reads and MFMA;
// one __syncthreads per slot. Cross-block overlap hides stage/drain waits.
__global__ __launch_bounds__(512, 4) void gemm_disp_kernel(
    const unsigned short* __restrict__ Phi, float* __restrict__ rowsum) {
    __shared__ short smem[2 * BUFSH];       // 48 KiB

    // XCD-aware swizzle (1056 = 8*132)
    int bid = blockIdx.x;
    int u = (bid & 7) * (NBLK / 8) + (bid >> 3);
    int i = 0;
    while (u >= NTJ - 2 * i) { u -= NTJ - 2 * i; ++i; }
    const int j = 2 * i + u;                // j >= 2i
    const bool diagovl = ((j >> 1) == i);   // col-range overlaps row-range

    const int w    = threadIdx.x >> 6;      // wave 0..7
    const int lane = threadIdx.x & 63;
    const int wr = w >> 1, wc = w & 1;      // 4x2 waves, 64x64 each
    const int h = lane >> 4;                // k-group 0..3
    const int r = lane & 15;                // fragment row/col
    const int seg = (h ^ ((r >> 1) & 3)) * 8;  // swizzled k-seg (shorts)

    const int Ibase = i * 256, Jbase = j * 128;

    f32x4 acc[4][4];
    #pragma unroll
    for (int m = 0; m < 4; ++m)
        #pragma unroll
        for (int n = 0; n < 4; ++n) acc[m][n] = (f32x4){0.f, 0.f, 0.f, 0.f};

    // staging: per slot 24 KiB = 24 loads; wave w: A rows [w*32,w*32+32) (2) +
    // B rows [w*16,w*16+16) (1). Linear LDS dest, inverse-swizzled source.
    const int srow = lane >> 2;             // 0..15
    const int sseg = (lane & 3) ^ ((lane >> 3) & 3);
    const unsigned short* gA =
        Phi + (size_t)(Ibase + w * 32 + srow) * FEAT + sseg * 8;
    const unsigned short* gB =
        Phi + (size_t)(Jbase + w * 16 + srow) * FEAT + sseg * 8;

#define STAGE(buf, s)                                                         \
    {                                                                         \
        short* la0 = smem + (buf) * BUFSH + (w * 32) * 32;                    \
        short* la1 = la0 + 16 * 32;                                           \
        short* lb  = smem + (buf) * BUFSH + 8192 + (w * 16) * 32;             \
        __builtin_amdgcn_global_load_lds(                                     \
            (const __attribute__((address_space(1))) void*)(gA + (s) * 32),   \
            (__attribute__((address_space(3))) void*)la0, 16, 0, 0);          \
        __builtin_amdgcn_global_load_lds(                                     \
            (const __attribute__((address_space(1))) void*)(gA + 16 * FEAT + (s) * 32), \
            (__attribute__((address_space(3))) void*)la1, 16, 0, 0);          \
        __builtin_amdgcn_global_load_lds(                                     \
            (const __attribute__((address_space(1))) void*)(gB + (s) * 32),   \
            (__attribute__((address_space(3))) void*)lb, 16, 0, 0);           \
    }

    STAGE(0, 0);

    for (int s = 0; s < NSLOT; ++s) {
        __syncthreads();                    // drains slot-s staging; all waves
                                            // past slot s-1 reads
        const short* As = smem + (s & 1) * BUFSH;
        const short* Bs = As + 8192;
        short8 a0, a1, a2, a3, b0, b1, b2, b3;
        b0 = *(const short8*)(Bs + (wc * 64 +  0 + r) * 32 + seg);
        b1 = *(const short8*)(Bs + (wc * 64 + 16 + r) * 32 + seg);
        b2 = *(const short8*)(Bs + (wc * 64 + 32 + r) * 32 + seg);
        b3 = *(const short8*)(Bs + (wc * 64 + 48 + r) * 32 + seg);
        a0 = *(const short8*)(As + (wr * 64 +  0 + r) * 32 + seg);
        a1 = *(const short8*)(As + (wr * 64 + 16 + r) * 32 + seg);
        a2 = *(const short8*)(As + (wr * 64 + 32 + r) * 32 + seg);
        a3 = *(const short8*)(As + (wr * 64 + 48 + r) * 32 + seg);
        if (s + 1 < NSLOT) STAGE((s + 1) & 1, s + 1);
        __builtin_amdgcn_s_setprio(1);
        #pragma unroll
        for (int n = 0; n < 4; ++n) {
            short8 bn = (n == 0) ? b0 : (n == 1) ? b1 : (n == 2) ? b2 : b3;
            acc[0][n] = __builtin_amdgcn_mfma_f32_16x16x32_bf16(a0, bn, acc[0][n], 0, 0, 0);
            acc[1][n] = __builtin_amdgcn_mfma_f32_16x16x32_bf16(a1, bn, acc[1][n], 0, 0, 0);
            acc[2][n] = __builtin_amdgcn_mfma_f32_16x16x32_bf16(a2, bn, acc[2][n], 0, 0, 0);
            acc[3][n] = __builtin_amdgcn_mfma_f32_16x16x32_bf16(a3, bn, acc[3][n], 0, 0, 0);
        }
        __builtin_amdgcn_s_setprio(0);
    }

    // epilogue: e = exp(10*S); zero exact diagonal on overlap blocks
    // D layout: row = 4*h + q, col = r (HW-verified)
    #pragma unroll
    for (int m = 0; m < 4; ++m)
        #pragma unroll
        for (int n = 0; n < 4; ++n)
            #pragma unroll
            for (int q = 0; q < 4; ++q) {
                float v = __expf(acc[m][n][q] * 10.0f);
                if (diagovl &&
                    (Ibase + wr * 64 + m * 16 + h * 4 + q) ==
                    (Jbase + wc * 64 + n * 16 + r))
                    v = 0.f;
                acc[m][n][q] = v;
            }

    // row credit (always): rowsum[Ibase + wr*64 + m*16 + 4h+q]
    #pragma unroll
    for (int m = 0; m < 4; ++m) {
        float rs[4];
        #pragma unroll
        for (int q = 0; q < 4; ++q)
            rs[q] = acc[m][0][q] + acc[m][1][q] + acc[m][2][q] + acc[m][3][q];
        #pragma unroll
        for (int q = 0; q < 4; ++q)
            #pragma unroll
            for (int off = 1; off < 16; off <<= 1) rs[q] += __shfl_xor(rs[q], off);
        if (r == 0) {
            #pragma unroll
            for (int q = 0; q < 4; ++q)
                atomicAdd(&rowsum[Ibase + wr * 64 + m * 16 + h * 4 + q], rs[q]);
        }
    }

    // col credit (only when mirror entry is NOT computed elsewhere): j >= 2i+2
    if (!diagovl) {
        #pragma unroll
        for (int n = 0; n < 4; ++n) {
            float cs = 0.f;
            #pragma unroll
            for (int m = 0; m < 4; ++m)
                #pragma unroll
                for (int q = 0; q < 4; ++q) cs += acc[m][n][q];
            cs += __shfl_xor(cs, 16);
            cs += __shfl_xor(cs, 32);
            if (lane < 16)
                atomicAdd(&rowsum[Jbase + wc * 64 + n * 16 + r], cs);
        }
    }
}

// ---------------- Kernel 3: loss = mean(log(rowsum / (n-1))) ---------------
__global__ __launch_bounds__(512) void loss_kernel(
    const float* __restrict__ rowsum, float* __restrict__ out) {
    __shared__ float red[8];
    float s = 0.f;
    for (int i = threadIdx.x; i < N_CLS; i += 512)
        s += logf(rowsum[i] * (1.0f / (float)(N_CLS - 1)));
    #pragma unroll
    for (int off = 32; off; off >>= 1) s += __shfl_xor(s, off);
    if ((threadIdx.x & 63) == 0) red[threadIdx.x >> 6] = s;
    __syncthreads();
    if (threadIdx.x == 0) {
        float tot = 0.f;
        #pragma unroll
        for (int i = 0; i < 8; ++i) tot += red[i];
        out[0] = tot * (1.0f / (float)N_CLS);
    }
}

extern "C" void kernel_launch(void* const* d_in, const int* in_sizes, int n_in,
                              void* d_out, int out_size, void* d_ws, size_t ws_size,
                              hipStream_t stream) {
    (void)in_sizes; (void)n_in; (void)out_size; (void)ws_size;
    const float* features = (const float*)d_in[0];
    const int*   labels   = (const int*)d_in[1];
    const float* protos   = (const float*)d_in[2];
    float* out = (float*)d_out;

    unsigned short* Phi = (unsigned short*)d_ws;                    // 8 MiB
    float* rowsum = (float*)(Phi + (size_t)N_CLS * FEAT);           // 32 KiB

    ema_kernel<<<N_CLS / 4, 256, 0, stream>>>(features, labels, protos, Phi, rowsum);
    gemm_disp_kernel<<<NBLK, 512, 0, stream>>>(Phi, rowsum);
    loss_kernel<<<1, 512, 0, stream>>>(rowsum, out);
}

// Round 7
// 70.406 us; speedup vs baseline: 1.5109x; 1.1505x over previous
//
#include <hip/hip_runtime.h>
#include <stdint.h>

#define N_CLS 8192
#define FEAT  512
#define BATCH 1024
#define NTI   32                            // 256-row tiles
#define NTJ   64                            // 128-col tiles
#define NBLK  1056                          // #{(i,j): j in [2i, 64)}
#define NSLOT 16                            // FEAT/32
#define BUFSH 12288                         // shorts/slot: A 256*32 + B 128*32

typedef __attribute__((ext_vector_type(8))) short short8;
typedef __attribute__((ext_vector_type(4))) float f32x4;

__device__ inline unsigned short f2bf(float x) {
    union { float f; unsigned int u; } v; v.f = x;
    unsigned int u = v.u;
    u += 0x7fffu + ((u >> 16) & 1u);        // RNE to bf16
    return (unsigned short)(u >> 16);
}

// ---------------- Kernel 1: sequential EMA per label -> bf16 protos --------
__global__ __launch_bounds__(256) void ema_kernel(
    const float* __restrict__ features, const int* __restrict__ labels,
    const float* __restrict__ protos,
    unsigned short* __restrict__ Phi, float* __restrict__ rowsum) {
    const int row  = blockIdx.x * 4 + (threadIdx.x >> 6);
    const int lane = threadIdx.x & 63;
    if (lane == 0) rowsum[row] = 0.f;

    float p[8];
    #pragma unroll
    for (int j = 0; j < 8; ++j) p[j] = protos[(size_t)row * FEAT + j * 64 + lane];

    for (int c = 0; c < BATCH / 64; ++c) {
        int lab = labels[c * 64 + lane];
        unsigned long long m = __ballot(lab == row);
        while (m) {
            int b = __builtin_ctzll(m);     // earliest remaining sample
            m &= m - 1;
            int s = c * 64 + b;
            float ss = 0.f;
            #pragma unroll
            for (int j = 0; j < 8; ++j) {
                float f = features[(size_t)s * FEAT + j * 64 + lane];
                p[j] = p[j] * 0.95f + f * 0.05f;
                ss += p[j] * p[j];
            }
            #pragma unroll
            for (int off = 32; off; off >>= 1) ss += __shfl_xor(ss, off);
            float inv = 1.0f / fmaxf(sqrtf(ss), 1e-12f);
            #pragma unroll
            for (int j = 0; j < 8; ++j) p[j] *= inv;
        }
    }
    #pragma unroll
    for (int j = 0; j < 8; ++j)
        Phi[(size_t)row * FEAT + j * 64 + lane] = f2bf(p[j]);
}

// ---------------- Kernel 2: 256x128 rect Gram tiles, ring-3 counted-vmcnt --
// R6 geometry (8 waves of 64x64, 2 blocks/CU) + T4: ring of 3 K-32 slots,
// staging 2 slots ahead, vmcnt(3) at slot end (never drained mid-loop),
// one raw s_barrier per slot.
__global__ __launch_bounds__(512, 4) void gemm_disp_kernel(
    const unsigned short* __restrict__ Phi, float* __restrict__ rowsum) {
    __shared__ short smem[3 * BUFSH];       // 72 KiB

    // XCD-aware swizzle (1056 = 8*132)
    int bid = blockIdx.x;
    int u = (bid & 7) * (NBLK / 8) + (bid >> 3);
    int i = 0;
    while (u >= NTJ - 2 * i) { u -= NTJ - 2 * i; ++i; }
    const int j = 2 * i + u;                // j >= 2i
    const bool diagovl = ((j >> 1) == i);   // col-range overlaps row-range

    const int w    = threadIdx.x >> 6;      // wave 0..7
    const int lane = threadIdx.x & 63;
    const int wr = w >> 1, wc = w & 1;      // 4x2 waves, 64x64 each
    const int h = lane >> 4;                // k-group 0..3
    const int r = lane & 15;                // fragment row/col
    const int seg = (h ^ ((r >> 1) & 3)) * 8;  // swizzled k-seg (shorts)

    const int Ibase = i * 256, Jbase = j * 128;

    f32x4 acc[4][4];
    #pragma unroll
    for (int m = 0; m < 4; ++m)
        #pragma unroll
        for (int n = 0; n < 4; ++n) acc[m][n] = (f32x4){0.f, 0.f, 0.f, 0.f};

    // staging: wave w covers A rows [w*32, w*32+32) (2 loads) + B rows
    // [w*16, w*16+16) (1 load). Linear LDS dest, inverse-swizzled source.
    const int srow = lane >> 2;             // 0..15
    const int sseg = (lane & 3) ^ ((lane >> 3) & 3);
    const unsigned short* gA =
        Phi + (size_t)(Ibase + w * 32 + srow) * FEAT + sseg * 8;
    const unsigned short* gB =
        Phi + (size_t)(Jbase + w * 16 + srow) * FEAT + sseg * 8;

#define STAGE(s)                                                              \
    {                                                                         \
        short* la0 = smem + ((s) % 3) * BUFSH + (w * 32) * 32;                \
        short* la1 = la0 + 16 * 32;                                           \
        short* lb  = smem + ((s) % 3) * BUFSH + 8192 + (w * 16) * 32;         \
        __builtin_amdgcn_global_load_lds(                                     \
            (const __attribute__((address_space(1))) void*)(gA + (s) * 32),   \
            (__attribute__((address_space(3))) void*)la0, 16, 0, 0);          \
        __builtin_amdgcn_global_load_lds(                                     \
            (const __attribute__((address_space(1))) void*)(gA + 16 * FEAT + (s) * 32), \
            (__attribute__((address_space(3))) void*)la1, 16, 0, 0);          \
        __builtin_amdgcn_global_load_lds(                                     \
            (const __attribute__((address_space(1))) void*)(gB + (s) * 32),   \
            (__attribute__((address_space(3))) void*)lb, 16, 0, 0);           \
    }

#define SLOT(s, TAIL)                                                         \
    {                                                                         \
        const short* As = smem + ((s) % 3) * BUFSH;                           \
        const short* Bs = As + 8192;                                          \
        short8 a0, a1, a2, a3, b0, b1, b2, b3;                                \
        b0 = *(const short8*)(Bs + (wc * 64 +  0 + r) * 32 + seg);            \
        b1 = *(const short8*)(Bs + (wc * 64 + 16 + r) * 32 + seg);            \
        b2 = *(const short8*)(Bs + (wc * 64 + 32 + r) * 32 + seg);            \
        b3 = *(const short8*)(Bs + (wc * 64 + 48 + r) * 32 + seg);            \
        a0 = *(const short8*)(As + (wr * 64 +  0 + r) * 32 + seg);            \
        a1 = *(const short8*)(As + (wr * 64 + 16 + r) * 32 + seg);            \
        a2 = *(const short8*)(As + (wr * 64 + 32 + r) * 32 + seg);            \
        a3 = *(const short8*)(As + (wr * 64 + 48 + r) * 32 + seg);            \
        __builtin_amdgcn_s_setprio(1);                                        \
        acc[0][0] = __builtin_amdgcn_mfma_f32_16x16x32_bf16(a0, b0, acc[0][0], 0, 0, 0); \
        acc[1][0] = __builtin_amdgcn_mfma_f32_16x16x32_bf16(a1, b0, acc[1][0], 0, 0, 0); \
        acc[2][0] = __builtin_amdgcn_mfma_f32_16x16x32_bf16(a2, b0, acc[2][0], 0, 0, 0); \
        acc[3][0] = __builtin_amdgcn_mfma_f32_16x16x32_bf16(a3, b0, acc[3][0], 0, 0, 0); \
        acc[0][1] = __builtin_amdgcn_mfma_f32_16x16x32_bf16(a0, b1, acc[0][1], 0, 0, 0); \
        acc[1][1] = __builtin_amdgcn_mfma_f32_16x16x32_bf16(a1, b1, acc[1][1], 0, 0, 0); \
        acc[2][1] = __builtin_amdgcn_mfma_f32_16x16x32_bf16(a2, b1, acc[2][1], 0, 0, 0); \
        acc[3][1] = __builtin_amdgcn_mfma_f32_16x16x32_bf16(a3, b1, acc[3][1], 0, 0, 0); \
        acc[0][2] = __builtin_amdgcn_mfma_f32_16x16x32_bf16(a0, b2, acc[0][2], 0, 0, 0); \
        acc[1][2] = __builtin_amdgcn_mfma_f32_16x16x32_bf16(a1, b2, acc[1][2], 0, 0, 0); \
        acc[2][2] = __builtin_amdgcn_mfma_f32_16x16x32_bf16(a2, b2, acc[2][2], 0, 0, 0); \
        acc[3][2] = __builtin_amdgcn_mfma_f32_16x16x32_bf16(a3, b2, acc[3][2], 0, 0, 0); \
        acc[0][3] = __builtin_amdgcn_mfma_f32_16x16x32_bf16(a0, b3, acc[0][3], 0, 0, 0); \
        acc[1][3] = __builtin_amdgcn_mfma_f32_16x16x32_bf16(a1, b3, acc[1][3], 0, 0, 0); \
        acc[2][3] = __builtin_amdgcn_mfma_f32_16x16x32_bf16(a2, b3, acc[2][3], 0, 0, 0); \
        acc[3][3] = __builtin_amdgcn_mfma_f32_16x16x32_bf16(a3, b3, acc[3][3], 0, 0, 0); \
        __builtin_amdgcn_s_setprio(0);                                        \
        TAIL                                                                  \
    }

#define TAIL_MID(s)                                                           \
    STAGE((s) + 2)                                                            \
    asm volatile("s_waitcnt vmcnt(3)" ::: "memory");                          \
    __builtin_amdgcn_s_barrier();
#define TAIL_14                                                               \
    asm volatile("s_waitcnt vmcnt(0)" ::: "memory");                          \
    __builtin_amdgcn_s_barrier();
#define TAIL_15

    // prologue: stage slots 0,1; wait slot 0 (slot 1 stays in flight)
    STAGE(0) STAGE(1)
    asm volatile("s_waitcnt vmcnt(3)" ::: "memory");
    __builtin_amdgcn_s_barrier();

    SLOT(0,  TAIL_MID(0))  SLOT(1,  TAIL_MID(1))  SLOT(2,  TAIL_MID(2))
    SLOT(3,  TAIL_MID(3))  SLOT(4,  TAIL_MID(4))  SLOT(5,  TAIL_MID(5))
    SLOT(6,  TAIL_MID(6))  SLOT(7,  TAIL_MID(7))  SLOT(8,  TAIL_MID(8))
    SLOT(9,  TAIL_MID(9))  SLOT(10, TAIL_MID(10)) SLOT(11, TAIL_MID(11))
    SLOT(12, TAIL_MID(12)) SLOT(13, TAIL_MID(13))
    SLOT(14, TAIL_14)
    SLOT(15, TAIL_15)

    // epilogue: e = exp(10*S); zero exact diagonal on overlap blocks
    // D layout: row = 4*h + q, col = r (HW-verified)
    #pragma unroll
    for (int m = 0; m < 4; ++m)
        #pragma unroll
        for (int n = 0; n < 4; ++n)
            #pragma unroll
            for (int q = 0; q < 4; ++q) {
                float v = __expf(acc[m][n][q] * 10.0f);
                if (diagovl &&
                    (Ibase + wr * 64 + m * 16 + h * 4 + q) ==
                    (Jbase + wc * 64 + n * 16 + r))
                    v = 0.f;
                acc[m][n][q] = v;
            }

    // row credit (always): rowsum[Ibase + wr*64 + m*16 + 4h+q]
    #pragma unroll
    for (int m = 0; m < 4; ++m) {
        float rs[4];
        #pragma unroll
        for (int q = 0; q < 4; ++q)
            rs[q] = acc[m][0][q] + acc[m][1][q] + acc[m][2][q] + acc[m][3][q];
        #pragma unroll
        for (int q = 0; q < 4; ++q)
            #pragma unroll
            for (int off = 1; off < 16; off <<= 1) rs[q] += __shfl_xor(rs[q], off);
        if (r == 0) {
            #pragma unroll
            for (int q = 0; q < 4; ++q)
                atomicAdd(&rowsum[Ibase + wr * 64 + m * 16 + h * 4 + q], rs[q]);
        }
    }

    // col credit (only when mirror entry is NOT computed elsewhere): j >= 2i+2
    if (!diagovl) {
        #pragma unroll
        for (int n = 0; n < 4; ++n) {
            float cs = 0.f;
            #pragma unroll
            for (int m = 0; m < 4; ++m)
                #pragma unroll
                for (int q = 0; q < 4; ++q) cs += acc[m][n][q];
            cs += __shfl_xor(cs, 16);
            cs += __shfl_xor(cs, 32);
            if (lane < 16)
                atomicAdd(&rowsum[Jbase + wc * 64 + n * 16 + r], cs);
        }
    }
}

// ---------------- Kernel 3: loss = mean(log(rowsum / (n-1))) ---------------
__global__ __launch_bounds__(512) void loss_kernel(
    const float* __restrict__ rowsum, float* __restrict__ out) {
    __shared__ float red[8];
    float s = 0.f;
    for (int i = threadIdx.x; i < N_CLS; i += 512)
        s += logf(rowsum[i] * (1.0f / (float)(N_CLS - 1)));
    #pragma unroll
    for (int off = 32; off; off >>= 1) s += __shfl_xor(s, off);
    if ((threadIdx.x & 63) == 0) red[threadIdx.x >> 6] = s;
    __syncthreads();
    if (threadIdx.x == 0) {
        float tot = 0.f;
        #pragma unroll
        for (int i = 0; i < 8; ++i) tot += red[i];
        out[0] = tot * (1.0f / (float)N_CLS);
    }
}

extern "C" void kernel_launch(void* const* d_in, const int* in_sizes, int n_in,
                              void* d_out, int out_size, void* d_ws, size_t ws_size,
                              hipStream_t stream) {
    (void)in_sizes; (void)n_in; (void)out_size; (void)ws_size;
    const float* features = (const float*)d_in[0];
    const int*   labels   = (const int*)d_in[1];
    const float* protos   = (const float*)d_in[2];
    float* out = (float*)d_out;

    unsigned short* Phi = (unsigned short*)d_ws;                    // 8 MiB
    float* rowsum = (float*)(Phi + (size_t)N_CLS * FEAT);           // 32 KiB

    ema_kernel<<<N_CLS / 4, 256, 0, stream>>>(features, labels, protos, Phi, rowsum);
    gemm_disp_kernel<<<NBLK, 512, 0, stream>>>(Phi, rowsum);
    loss_kernel<<<1, 512, 0, stream>>>(rowsum, out);
}